// Round 5
// baseline (66.515 us; speedup 1.0000x reference)
//
#include <hip/hip_runtime.h>
#include <cstdint>
#include <cstddef>

#define Bb 128
#define Cc 64
#define Dd 365
#define Tt 364
#define Ss 32
#define SM1 31
#define NIJ 961
#define BASISF 1e-10f

typedef _Float16 f16x8 __attribute__((ext_vector_type(8)));
typedef float f32x4 __attribute__((ext_vector_type(4)));
typedef float f32x2 __attribute__((ext_vector_type(2)));

// ---------------------------------------------------------------------------
// Prep: permuted+padded Bt[1024][64] f16 and mu_perm[1024] f32.
// MFMA column index m <-> (i, j):  i = m>>5, v = m&31, p = v>>4, je = v&15,
// j = 2*je + p.  (Even/odd interleave: each lane ends up with adjacent j's ->
// dwordx2 stores, and the diagonal-shift neighbor for odd j is lane-local.)
// ---------------------------------------------------------------------------
__global__ void prep_kernel(const float* __restrict__ mu,
                            const float* __restrict__ beta,
                            _Float16* __restrict__ Bt,
                            float* __restrict__ mu_perm) {
    int idx = blockIdx.x * blockDim.x + threadIdx.x;   // 0 .. 65535
    int m = idx >> 6, c = idx & 63;
    int i = m >> 5, v = m & 31, p = v >> 4, je = v & 15, j = 2 * je + p;
    float val = (i < SM1 && j < SM1) ? beta[c * NIJ + i * SM1 + j] : 0.0f;
    Bt[(size_t)m * Cc + c] = (_Float16)val;
    if (idx < 1024) {
        int ii = idx >> 5, vv = idx & 31, pp = vv >> 4, jj = 2 * (vv & 15) + pp;
        mu_perm[idx] = (ii < SM1 && jj < SM1) ? mu[ii * SM1 + jj] : 0.0f;
    }
}

// ---- DPP helpers (row ops within 16-lane rows; pure VALU, no DS pipe) ----
template <int CTRL>
__device__ __forceinline__ float dpp_add(float s) {
    union { float f; int i; } u, v;
    u.f = s;
    v.i = __builtin_amdgcn_update_dpp(0, u.i, CTRL, 0xf, 0xf, true);
    return s + v.f;
}
__device__ __forceinline__ float dpp_shr1(float x) {   // lane i <- lane i-1
    union { float f; int i; } u, v;
    u.f = x;
    v.i = __builtin_amdgcn_update_dpp(0, u.i, 0x111, 0xf, 0xf, true);
    return v.f;
}

// ---------------------------------------------------------------------------
// Main kernel: 512 threads = 8 waves; block = 32 bt-rows x 1024 m-cols.
// Wave w: bt-half mh = w>>2 (A-rows), m-quarter nq = w&3 (8 output i-rows).
// Software-pipelined by one q: iter q = {prefetch B(q+2), MFMA(q+1),
// epilogue(q)} so MFMA latency hides under the previous row's VALU epilogue.
// mu in registers; nontemporal dwordx2 stores.
// ---------------------------------------------------------------------------
__global__ __launch_bounds__(512, 4)
void transition_mfma_kernel(const float* __restrict__ adstock,
                            const _Float16* __restrict__ Bt,
                            const float* __restrict__ mu_perm,
                            float* __restrict__ out)
{
    const int bt0 = blockIdx.x * 32;
    const int tid = threadIdx.x;
    const int lane = tid & 63;
    const int w   = tid >> 6;
    const int je  = lane & 15;
    const int grp = lane >> 4;
    const int mh  = w >> 2;
    const int nq  = w & 3;

    __shared__ __align__(16) _Float16 Alds[32][72];   // 4.5 KB

    // ---- mu -> registers (L2-resident; issued before the A-staging sync) ----
    float mu_e[8], mu_o[8];
    #pragma unroll
    for (int q = 0; q < 8; ++q) {
        const int i = nq * 8 + q;
        mu_e[q] = mu_perm[i * 32 + je];
        mu_o[q] = mu_perm[i * 32 + 16 + je];
    }

    // ---- stage A tile (f32 -> f16) ----
    for (int e = tid; e < 32 * Cc; e += 512) {
        int c = e >> 5, m = e & 31;
        int bt = bt0 + m, b = bt / Tt, t = bt - b * Tt;
        Alds[m][c] = (_Float16)adstock[((size_t)b * Cc + c) * Dd + 1 + t];
    }
    __syncthreads();

    const int arow = mh * 16 + je;
    const f16x8 a0 = *reinterpret_cast<const f16x8*>(&Alds[arow][grp * 8]);
    const f16x8 a1 = *reinterpret_cast<const f16x8*>(&Alds[arow][32 + grp * 8]);

    // lane base into Bt; B(q) frags at bp + q*2048 + {0, 32, 1024, 1056}
    const _Float16* bp = Bt + ((size_t)(nq * 256 + je)) * Cc + grp * 8;

    const float omask = (je == 15) ? 0.0f : 1.0f;   // mask padded j=31 in den

    float* outp[4];
    #pragma unroll
    for (int r = 0; r < 4; ++r)
        outp[r] = out + ((size_t)(bt0 + mh * 16 + grp * 4 + r)) * 1024
                      + nq * 256 + je * 2;
    // store for (q, r): outp[r] + q*32

    // ---- pipeline state ----
    f16x8 Bf[2][4];
    f32x4 acc[2][2];

    #pragma unroll
    for (int u = 0; u < 4; ++u) {
        static const int off[4] = {0, 32, 1024, 1056};
        Bf[0][u] = *reinterpret_cast<const f16x8*>(bp + off[u]);
    }
    {
        f32x4 z = {0.f, 0.f, 0.f, 0.f};
        f32x4 t0 = __builtin_amdgcn_mfma_f32_16x16x32_f16(a0, Bf[0][0], z, 0, 0, 0);
        acc[0][0] = __builtin_amdgcn_mfma_f32_16x16x32_f16(a1, Bf[0][1], t0, 0, 0, 0);
        f32x4 t1 = __builtin_amdgcn_mfma_f32_16x16x32_f16(a0, Bf[0][2], z, 0, 0, 0);
        acc[0][1] = __builtin_amdgcn_mfma_f32_16x16x32_f16(a1, Bf[0][3], t1, 0, 0, 0);
    }
    #pragma unroll
    for (int u = 0; u < 4; ++u) {
        static const int off[4] = {0, 32, 1024, 1056};
        Bf[1][u] = *reinterpret_cast<const f16x8*>(bp + 2048 + off[u]);
    }

    #pragma unroll
    for (int q = 0; q < 8; ++q) {
        const int cur = q & 1, nxt = cur ^ 1;

        // 1. prefetch B(q+2) into the buffer whose contents were consumed
        if (q < 6) {
            const _Float16* np = bp + (size_t)(q + 2) * 2048;
            Bf[cur][0] = *reinterpret_cast<const f16x8*>(np + 0);
            Bf[cur][1] = *reinterpret_cast<const f16x8*>(np + 32);
            Bf[cur][2] = *reinterpret_cast<const f16x8*>(np + 1024);
            Bf[cur][3] = *reinterpret_cast<const f16x8*>(np + 1056);
        }

        // 2. MFMAs for q+1 (B loaded one full iteration ago)
        if (q < 7) {
            f32x4 z = {0.f, 0.f, 0.f, 0.f};
            f32x4 t0 = __builtin_amdgcn_mfma_f32_16x16x32_f16(a0, Bf[nxt][0], z, 0, 0, 0);
            acc[nxt][0] = __builtin_amdgcn_mfma_f32_16x16x32_f16(a1, Bf[nxt][1], t0, 0, 0, 0);
            f32x4 t1 = __builtin_amdgcn_mfma_f32_16x16x32_f16(a0, Bf[nxt][2], z, 0, 0, 0);
            acc[nxt][1] = __builtin_amdgcn_mfma_f32_16x16x32_f16(a1, Bf[nxt][3], t1, 0, 0, 0);
        }

        // 3. epilogue for q on acc[cur]
        const int i = nq * 8 + q;            // output row (wave-uniform)
        if (i == SM1) {
            f32x2 vv;
            vv.x = BASISF;
            vv.y = (je == 15) ? (1.0f - SM1 * BASISF) : BASISF;
            #pragma unroll
            for (int r = 0; r < 4; ++r)
                __builtin_nontemporal_store(vv,
                    reinterpret_cast<f32x2*>(outp[r] + q * 32));
        } else {
            const int j_e = 2 * je, j_o = 2 * je + 1;
            #pragma unroll
            for (int r = 0; r < 4; ++r) {
                float ne = __expf(acc[cur][0][r] - mu_e[q]);  // num[j = 2*je]
                float no = __expf(acc[cur][1][r] - mu_o[q]);  // num[j = 2*je+1]
                float s = fmaf(no, omask, ne);
                s = dpp_add<0x128>(s);               // row_ror:8
                s = dpp_add<0x124>(s);               // row_ror:4
                s = dpp_add<0x122>(s);               // row_ror:2
                s = dpp_add<0x121>(s);               // row_ror:1
                const float inv = __builtin_amdgcn_rcpf(1.0f + s);  // Q_same
                const float she = dpp_shr1(no);      // num[2*je - 1]
                const float pe = ne * inv, po = no * inv, pse = she * inv;
                float ve = (j_e < i) ? pe : ((j_e == i) ? inv : pse);
                float vo = (j_o < i) ? po : ((j_o == i) ? inv : pe);
                f32x2 vv;
                vv.x = fmaxf(ve, BASISF);
                vv.y = fmaxf(vo, BASISF);
                __builtin_nontemporal_store(vv,
                    reinterpret_cast<f32x2*>(outp[r] + q * 32));
            }
        }
    }
}

// ---------------------------------------------------------------------------
// Fallback (no workspace): round-1 scalar kernel.
// ---------------------------------------------------------------------------
__global__ __launch_bounds__(256, 4)
void transition_fallback_kernel(const float* __restrict__ adstock,
                                const float* __restrict__ beta,
                                const float* __restrict__ mu,
                                float* __restrict__ out) {
    const int b  = blockIdx.x;
    const int t0 = blockIdx.y * 16;
    const int tid = threadIdx.x;

    __shared__ float adT[Cc][16];
    __shared__ float num_lds[8][964];

    for (int k = tid; k < Cc * 16; k += 256) {
        int c = k >> 4, tt = k & 15, t = t0 + tt;
        adT[c][tt] = (t < Tt) ? adstock[(size_t)b * (Cc * Dd) + c * Dd + 1 + t] : 0.0f;
    }
    __syncthreads();

    const int ij0 = tid * 4;
    const bool active = (ij0 < 964);
    float acc[16][4];
    #pragma unroll
    for (int tt = 0; tt < 16; ++tt) { acc[tt][0]=0;acc[tt][1]=0;acc[tt][2]=0;acc[tt][3]=0; }

    if (active) {
        for (int c = 0; c < Cc; ++c) {
            const float* bsrc = beta + (size_t)c * NIJ;
            float w0 = (ij0+0<NIJ)?bsrc[ij0+0]:0.f, w1 = (ij0+1<NIJ)?bsrc[ij0+1]:0.f;
            float w2 = (ij0+2<NIJ)?bsrc[ij0+2]:0.f, w3 = (ij0+3<NIJ)?bsrc[ij0+3]:0.f;
            #pragma unroll
            for (int tt = 0; tt < 16; ++tt) {
                float a = adT[c][tt];
                acc[tt][0] = fmaf(a, w0, acc[tt][0]);
                acc[tt][1] = fmaf(a, w1, acc[tt][1]);
                acc[tt][2] = fmaf(a, w2, acc[tt][2]);
                acc[tt][3] = fmaf(a, w3, acc[tt][3]);
            }
        }
    }
    float m0=0,m1=0,m2=0,m3=0;
    if (active) {
        m0 = (ij0+0<NIJ)?mu[ij0+0]:0.f; m1 = (ij0+1<NIJ)?mu[ij0+1]:0.f;
        m2 = (ij0+2<NIJ)?mu[ij0+2]:0.f; m3 = (ij0+3<NIJ)?mu[ij0+3]:0.f;
    }
    const int q8 = tid >> 5, irow = tid & 31;
    #pragma unroll
    for (int half = 0; half < 2; ++half) {
        if (active) {
            #pragma unroll
            for (int q = 0; q < 8; ++q) {
                const int tt = half * 8 + q;
                num_lds[q][ij0+0] = __expf(acc[tt][0] - m0);
                num_lds[q][ij0+1] = __expf(acc[tt][1] - m1);
                num_lds[q][ij0+2] = __expf(acc[tt][2] - m2);
                num_lds[q][ij0+3] = __expf(acc[tt][3] - m3);
            }
        }
        __syncthreads();
        const int t = t0 + half * 8 + q8;
        if (t < Tt) {
            float* op = out + (((size_t)b * Tt + t) * Ss + irow) * Ss;
            if (irow < SM1) {
                float row[SM1]; float den = 1.0f;
                #pragma unroll
                for (int j = 0; j < SM1; ++j) { row[j] = num_lds[q8][irow*SM1+j]; den += row[j]; }
                const float inv = 1.0f / den;
                #pragma unroll
                for (int j = 0; j < Ss; ++j) {
                    float v = (j < irow) ? row[j]*inv : ((j == irow) ? inv
                              : (j-1 < SM1 ? row[j-1]*inv : 0.f));
                    op[j] = fmaxf(v, BASISF);
                }
            } else {
                #pragma unroll
                for (int j = 0; j < Ss; ++j) op[j] = (j == SM1) ? (1.0f - SM1*BASISF) : BASISF;
            }
        }
        __syncthreads();
    }
}

// ---------------------------------------------------------------------------
extern "C" void kernel_launch(void* const* d_in, const int* in_sizes, int n_in,
                              void* d_out, int out_size, void* d_ws, size_t ws_size,
                              hipStream_t stream) {
    const float* adstock = (const float*)d_in[0];
    const float* mu      = (const float*)d_in[1];
    const float* beta    = (const float*)d_in[2];
    float* out = (float*)d_out;

    const size_t need = (size_t)1024 * Cc * sizeof(_Float16) + 1024 * sizeof(float);

    if (ws_size >= need) {
        _Float16* Bt = (_Float16*)d_ws;
        float* mu_perm = (float*)((char*)d_ws + (size_t)1024 * Cc * sizeof(_Float16));
        prep_kernel<<<(1024 * Cc) / 256, 256, 0, stream>>>(mu, beta, Bt, mu_perm);
        const int nblocks = (Bb * Tt) / 32;   // 1456
        transition_mfma_kernel<<<nblocks, 512, 0, stream>>>(adstock, Bt, mu_perm, out);
    } else {
        dim3 grid(Bb, (Tt + 15) / 16);
        transition_fallback_kernel<<<grid, 256, 0, stream>>>(adstock, beta, mu, out);
    }
}